// Round 6
// baseline (105.292 us; speedup 1.0000x reference)
//
#include <hip/hip_runtime.h>
#include <cstdint>
#include <cstddef>

#define PP 64
#define KK 8
#define HH 32
#define DD 2048
#define RR (PP*HH)        // 2048 center rows

typedef __attribute__((ext_vector_type(4))) float  f32x4;
typedef __attribute__((ext_vector_type(4))) float  float4v;
typedef __attribute__((ext_vector_type(8))) __bf16 bf16x8;

__device__ __forceinline__ unsigned short f2bf(float f) {
  unsigned int u = __builtin_bit_cast(unsigned int, f);
  u += 0x7fffu + ((u >> 16) & 1u);
  return (unsigned short)(u >> 16);
}

__device__ __forceinline__ void gload_lds16(const void* g, void* l) {
  __builtin_amdgcn_global_load_lds(
      (const __attribute__((address_space(1))) void*)g,
      (__attribute__((address_space(3))) void*)l, 16, 0, 0);
}

// K1: centers (mean over K), bf16 centers, row norms. No feature copy.
__global__ __launch_bounds__(256) void k_centers(const float* __restrict__ feat,
    unsigned short* __restrict__ cbf, float* __restrict__ cnorm,
    float* __restrict__ fnorm) {
  int row = blockIdx.x;            // p*32 + h
  int p = row >> 5, h = row & 31;
  int tid = threadIdx.x;
  int d0 = tid * 8;
  float c[8];
  float red[9];
  #pragma unroll
  for (int e = 0; e < 8; ++e) c[e] = 0.f;
  #pragma unroll
  for (int k = 0; k < KK; ++k) {
    const float* src = feat + ((size_t)((p*KK + k)*HH + h))*DD + d0;
    float4v f0 = *(const float4v*)src;
    float4v f1 = *(const float4v*)(src + 4);
    float s = 0.f;
    #pragma unroll
    for (int e = 0; e < 4; ++e) {
      c[e]   += f0[e];
      c[4+e] += f1[e];
      s += f0[e]*f0[e] + f1[e]*f1[e];
    }
    red[k] = s;
  }
  float csq = 0.f;
  #pragma unroll
  for (int e = 0; e < 8; ++e) { c[e] *= 0.125f; csq += c[e]*c[e]; }
  unsigned int pk[4];
  #pragma unroll
  for (int e = 0; e < 4; ++e)
    pk[e] = (unsigned int)f2bf(c[2*e]) | ((unsigned int)f2bf(c[2*e+1]) << 16);
  *(uint4*)(cbf + (size_t)row*DD + d0) = make_uint4(pk[0], pk[1], pk[2], pk[3]);
  red[8] = csq;

  __shared__ float lred[4][9];
  int lane = tid & 63, wv = tid >> 6;
  #pragma unroll
  for (int r = 0; r < 9; ++r) {
    float v = red[r];
    #pragma unroll
    for (int off = 32; off > 0; off >>= 1) v += __shfl_down(v, off, 64);
    if (lane == 0) lred[wv][r] = v;
  }
  __syncthreads();
  if (tid < 9) {
    float s = lred[0][tid] + lred[1][tid] + lred[2][tid] + lred[3][tid];
    if (tid < 8) fnorm[((size_t)(p*KK + tid))*HH + h] = s;
    else         cnorm[row] = s;
  }
}

// K2: merged Gram kernel.
// Blocks 0..527  : inter (symmetric upper-tri 64x64 tiles, XCD-swizzled, proven R4/R5 path).
// Blocks 528..1039: intra (class p, 32-feature block jb; A=centers bf16, B=features fp32
//                   read straight from L3 with pair-XOR-swizzled LDS, trunc-pack to bf16).
__global__ __launch_bounds__(256) void k_gram(const unsigned short* __restrict__ cbf,
    const float* __restrict__ feat, const float* __restrict__ cnorm,
    const float* __restrict__ fnorm, float* __restrict__ dm) {
  __shared__ char smem[32768];
  int tid = threadIdx.x, lane = tid & 63, w = tid >> 6;
  int ln = lane & 15, kq = lane >> 4;

  if (blockIdx.x < 528) {
    // ---------------- inter path ----------------
    unsigned short* Ab = (unsigned short*)smem;             // [2][4096]
    unsigned short* Bb = (unsigned short*)(smem + 16384);   // [2][4096]
    int bid = (blockIdx.x & 7)*66 + (blockIdx.x >> 3);      // 528 = 8*66, bijective
    int tI = 0, rem = bid;
    while (rem >= 32 - tI) { rem -= 32 - tI; ++tI; }
    int tJ = tI + rem;
    int wr = w >> 1, wc = w & 1;
    f32x4 acc[2][2];
    #pragma unroll
    for (int a = 0; a < 2; ++a)
      #pragma unroll
      for (int b = 0; b < 2; ++b)
        #pragma unroll
        for (int e = 0; e < 4; ++e) acc[a][b][e] = 0.f;

    int sr = lane >> 3, sc = lane & 7;
    int jch0 = sc ^ sr;
    const unsigned short* gA0 = cbf + (size_t)(tI*64 + w*16 + sr)*DD + jch0*8;
    const unsigned short* gB0 = cbf + (size_t)(tJ*64 + w*16 + sr)*DD + jch0*8;
    int lofs = w*1024 + lane*8;

    int aoff[2][2], boff[2][2];
    #pragma unroll
    for (int ks = 0; ks < 2; ++ks) {
      int phys = ((ks*4 + kq) ^ (ln & 7))*8;
      #pragma unroll
      for (int mt = 0; mt < 2; ++mt) {
        aoff[ks][mt] = (wr*32 + mt*16 + ln)*64 + phys;
        boff[ks][mt] = (wc*32 + mt*16 + ln)*64 + phys;
      }
    }

    gload_lds16(gA0,        Ab + lofs);
    gload_lds16(gA0 + 8*DD, Ab + lofs + 512);
    gload_lds16(gB0,        Bb + lofs);
    gload_lds16(gB0 + 8*DD, Bb + lofs + 512);
    asm volatile("s_waitcnt vmcnt(0)" ::: "memory");
    __builtin_amdgcn_s_barrier();

    int cur = 0;
    for (int t = 0; t < 32; ++t) {
      if (t < 31) {
        int k0 = (t + 1) * 64;
        gload_lds16(gA0 + k0,        Ab + (cur^1)*4096 + lofs);
        gload_lds16(gA0 + 8*DD + k0, Ab + (cur^1)*4096 + lofs + 512);
        gload_lds16(gB0 + k0,        Bb + (cur^1)*4096 + lofs);
        gload_lds16(gB0 + 8*DD + k0, Bb + (cur^1)*4096 + lofs + 512);
      }
      #pragma unroll
      for (int ks = 0; ks < 2; ++ks) {
        bf16x8 af[2], bfr[2];
        #pragma unroll
        for (int mt = 0; mt < 2; ++mt) {
          af[mt]  = *(const bf16x8*)(Ab + cur*4096 + aoff[ks][mt]);
          bfr[mt] = *(const bf16x8*)(Bb + cur*4096 + boff[ks][mt]);
        }
        #pragma unroll
        for (int mt = 0; mt < 2; ++mt)
          #pragma unroll
          for (int nt = 0; nt < 2; ++nt)
            acc[mt][nt] = __builtin_amdgcn_mfma_f32_16x16x32_bf16(af[mt], bfr[nt], acc[mt][nt], 0, 0, 0);
      }
      asm volatile("s_waitcnt vmcnt(0)" ::: "memory");
      __builtin_amdgcn_s_barrier();
      cur ^= 1;
    }

    int a = tI*2 + wr, b = tJ*2 + wc;
    if (a < b) {
      #pragma unroll
      for (int mt = 0; mt < 2; ++mt) {
        #pragma unroll
        for (int nt = 0; nt < 2; ++nt) {
          int j  = nt*16 + ln;
          int cc = tJ*64 + wc*32 + j;
          float nc = cnorm[cc];
          #pragma unroll
          for (int v = 0; v < 4; ++v) {
            int i  = mt*16 + kq*4 + v;
            int rr = tI*64 + wr*32 + i;
            float d2 = cnorm[rr] + nc - 2.f*acc[mt][nt][v];
            float t = tanhf(0.5f*sqrtf(fmaxf(d2, 1e-12f)));
            dm[(((size_t)a*64 + b) << 10) + ((size_t)i << 5) + j] = t;
          }
        }
      }
    }
  } else {
    // ---------------- intra path ----------------
    int bid = (int)blockIdx.x - 528;
    int p = bid >> 3, jb = bid & 7;
    int ks = w >> 1, nt = w & 1;
    unsigned short* A16 = (unsigned short*)smem;   // [2][2048] bf16 (8 KB)
    float*          B32 = (float*)(smem + 8192);   // [2][2048] f32  (16 KB)
    f32x4 acc[2];
    #pragma unroll
    for (int mi = 0; mi < 2; ++mi)
      #pragma unroll
      for (int e = 0; e < 4; ++e) acc[mi][e] = 0.f;

    // A staging: lane tid stages 16B. LDS byte = tid*16 -> row=tid>>3, physchunk=tid&7.
    // logical chunk = phys ^ (row&7)  (pre-swizzled global source).
    int arow = tid >> 3;
    int alog = (tid & 7) ^ (arow & 7);
    const unsigned short* gA = cbf + (size_t)(p*32 + arow)*DD + alog*8;

    // B staging: 2 rounds q; LDS byte = q*4096 + w*1024 + lane*16
    //   -> row = q*16 + w*4 + (lane>>4), pair=(lane>>1)&7, sub=lane&1
    //   logical pair = pair ^ ((row>>1)&7); global col = lp*8 + sub*4
    const float* gBrow[2];
    #pragma unroll
    for (int q = 0; q < 2; ++q) {
      int r  = q*16 + w*4 + (lane >> 4);
      int lp = ((lane >> 1) & 7) ^ ((r >> 1) & 7);
      int col = lp*8 + (lane & 1)*4;
      gBrow[q] = feat + (size_t)(p*256 + jb*32 + r)*DD + col;
    }

    // fragment offsets
    int kq8 = ks*4 + kq;
    int aofs[2];
    #pragma unroll
    for (int mi = 0; mi < 2; ++mi) {
      int row = mi*16 + ln;
      aofs[mi] = row*64 + (kq8 ^ (row & 7))*8;     // bf16 elements
    }
    int rB = nt*16 + ln;
    int bofs = rB*64 + (kq8 ^ ((rB >> 1) & 7))*8;  // f32 elements

    gload_lds16(gA, A16 + tid*8);
    gload_lds16(gBrow[0], B32 + w*256 + lane*4);
    gload_lds16(gBrow[1], B32 + 1024 + w*256 + lane*4);
    asm volatile("s_waitcnt vmcnt(0)" ::: "memory");
    __builtin_amdgcn_s_barrier();

    int cur = 0;
    for (int t = 0; t < 32; ++t) {
      if (t < 31) {
        int k0 = (t + 1) * 64;
        gload_lds16(gA + k0,       A16 + (cur^1)*2048 + tid*8);
        gload_lds16(gBrow[0] + k0, B32 + (cur^1)*2048 + w*256 + lane*4);
        gload_lds16(gBrow[1] + k0, B32 + (cur^1)*2048 + 1024 + w*256 + lane*4);
      }
      const float* bp = B32 + cur*2048 + bofs;
      f32x4 b0 = *(const f32x4*)bp;
      f32x4 b1 = *(const f32x4*)(bp + 4);
      unsigned int pk[4];
      #pragma unroll
      for (int e = 0; e < 2; ++e) {
        unsigned int a0 = __builtin_bit_cast(unsigned int, b0[2*e]);
        unsigned int a1 = __builtin_bit_cast(unsigned int, b0[2*e+1]);
        unsigned int c0 = __builtin_bit_cast(unsigned int, b1[2*e]);
        unsigned int c1 = __builtin_bit_cast(unsigned int, b1[2*e+1]);
        pk[e]   = (a0 >> 16) | (a1 & 0xffff0000u);
        pk[2+e] = (c0 >> 16) | (c1 & 0xffff0000u);
      }
      bf16x8 bv = __builtin_bit_cast(bf16x8, pk);
      #pragma unroll
      for (int mi = 0; mi < 2; ++mi) {
        bf16x8 af = *(const bf16x8*)(A16 + cur*2048 + aofs[mi]);
        acc[mi] = __builtin_amdgcn_mfma_f32_16x16x32_bf16(af, bv, acc[mi], 0, 0, 0);
      }
      asm volatile("s_waitcnt vmcnt(0)" ::: "memory");
      __builtin_amdgcn_s_barrier();
      cur ^= 1;
    }

    // K-split reduce: waves 2,3 (ks=1) -> waves 0,1 (ks=0), matched nt
    float* fb = (float*)smem;
    __syncthreads();
    if (w >= 2) {
      #pragma unroll
      for (int mi = 0; mi < 2; ++mi)
        *(f32x4*)(fb + ((w - 2)*2 + mi)*256 + lane*4) = acc[mi];
    }
    __syncthreads();
    if (w < 2) {
      #pragma unroll
      for (int mi = 0; mi < 2; ++mi)
        acc[mi] += *(const f32x4*)(fb + (w*2 + mi)*256 + lane*4);
      int cl = jb*32 + nt*16 + ln;
      float nf = fnorm[(size_t)p*256 + cl];
      #pragma unroll
      for (int mi = 0; mi < 2; ++mi) {
        #pragma unroll
        for (int v = 0; v < 4; ++v) {
          int i = mi*16 + kq*4 + v;
          float d2 = cnorm[p*32 + i] + nf - 2.f*acc[mi][v];
          float t = tanhf(0.5f*sqrtf(fmaxf(d2, 1e-12f)));
          dm[((size_t)(4096 + p*8 + jb) << 10) + ((size_t)i << 5) + (nt*16 + ln)] = t;
        }
      }
    }
  }
}

// K3: anti-diagonal wavefront DP, 32 lanes per pair, 8 pairs per block.
// Blocks 0..251: inter upper-tri pairs (2016) with mirror write; 252..315: intra.
__global__ __launch_bounds__(256) void k_dp(const float* __restrict__ dm,
                                            float* __restrict__ outF) {
  __shared__ float tile[8*1024];
  int t = threadIdx.x;
  int pl = t >> 5, j32 = t & 31;
  int bi = blockIdx.x;
  size_t tbase;
  float *optr0, *optr1;
  if (bi < 252) {
    int q = bi*8 + pl;
    int a = 0, rem = q;
    while (rem >= 63 - a) { rem -= 63 - a; ++a; }
    int b = a + 1 + rem;
    tbase = ((size_t)a*64 + b) << 10;
    optr0 = outF + a*64 + b;
    optr1 = outF + b*64 + a;
  } else {
    int q = (bi - 252)*8 + pl;
    tbase = ((size_t)(4096 + q)) << 10;
    optr0 = outF + 4096 + q;
    optr1 = nullptr;
  }
  const float4v* src = (const float4v*)(dm + tbase);
  float4v* dst = (float4v*)&tile[pl << 10];
  #pragma unroll
  for (int r = 0; r < 8; ++r) dst[r*32 + j32] = src[r*32 + j32];
  __syncthreads();
  const float INF = __builtin_inff();
  const float* mt = &tile[pl << 10];
  float A = INF;
  for (int d = 0; d < 63; ++d) {
    float left = __shfl_up(A, 1, 32);
    if (j32 == 0) left = INF;
    int i = d - j32;
    int ii = i < 0 ? 0 : (i > 31 ? 31 : i);
    float dv = mt[(ii << 5) + j32];
    float up = (i == 0) ? (j32 == 0 ? 0.f : INF) : A;
    A = (i >= 0 && i < 32) ? (fminf(up, left) + dv) : INF;
  }
  if (j32 == 31) {
    *optr0 = A;
    if (optr1) *optr1 = A;
  }
}

// K4: reductions + loss. out = [loss, intra_max[64], inter_min[64]]
__global__ __launch_bounds__(64) void k_final(const float* __restrict__ inter_full,
    const float* __restrict__ intra_pk, float* __restrict__ out) {
  int p = threadIdx.x;
  const float INF = __builtin_inff();
  float mn = INF;
  #pragma unroll 8
  for (int b = 0; b < 64; ++b)
    if (b != p) mn = fminf(mn, inter_full[p*64 + b]);
  float mx = -INF;
  #pragma unroll
  for (int k = 0; k < 8; ++k) mx = fmaxf(mx, intra_pk[p*8 + k]);
  out[1 + p]  = mx;
  out[65 + p] = mn;
  float v = fmaxf(mx - mn + 10.0f, 0.0f);
  #pragma unroll
  for (int off = 32; off > 0; off >>= 1) v += __shfl_down(v, off, 64);
  if (p == 0) out[0] = v * (1.0f/64.0f);
}

extern "C" void kernel_launch(void* const* d_in, const int* in_sizes, int n_in,
                              void* d_out, int out_size, void* d_ws, size_t ws_size,
                              hipStream_t stream) {
  const float* feat = (const float*)d_in[0];
  float* out = (float*)d_out;
  char* w = (char*)d_ws;
  // workspace layout (bytes)
  unsigned short* cbf = (unsigned short*)w;                 // 8,388,608
  float* cnorm        = (float*)(w + 8388608);              // 8,192
  float* fnorm        = (float*)(w + 8396800);              // 65,536
  float* dm_all       = (float*)(w + 8462336);              // (4096+512)*1024*4 = 18,874,368
  float* inter_full   = (float*)(w + 27336704);             // 16,384
  float* intra_pk     = (float*)(w + 27353088);             // 2,048 (contiguous after inter_full)
  // total ~27.4 MB

  k_centers<<<RR, 256, 0, stream>>>(feat, cbf, cnorm, fnorm);
  k_gram<<<1040, 256, 0, stream>>>(cbf, feat, cnorm, fnorm, dm_all);  // inter + intra merged
  k_dp<<<316, 256, 0, stream>>>(dm_all, inter_full);
  k_final<<<1, 64, 0, stream>>>(inter_full, intra_pk, out);
}

// Round 7
// 87.921 us; speedup vs baseline: 1.1976x; 1.1976x over previous
//
#include <hip/hip_runtime.h>
#include <cstdint>
#include <cstddef>

#define PP 64
#define KK 8
#define HH 32
#define DD 2048
#define RR (PP*HH)        // 2048 center rows

typedef __attribute__((ext_vector_type(4))) float  f32x4;
typedef __attribute__((ext_vector_type(4))) float  float4v;
typedef __attribute__((ext_vector_type(8))) __bf16 bf16x8;

__device__ __forceinline__ unsigned short f2bf(float f) {
  unsigned int u = __builtin_bit_cast(unsigned int, f);
  u += 0x7fffu + ((u >> 16) & 1u);
  return (unsigned short)(u >> 16);
}

__device__ __forceinline__ void gload_lds16(const void* g, void* l) {
  __builtin_amdgcn_global_load_lds(
      (const __attribute__((address_space(1))) void*)g,
      (__attribute__((address_space(3))) void*)l, 16, 0, 0);
}

// Proven 63-step anti-diagonal wavefront DP over a 32x32 tile (lanes 0..31 active).
__device__ __forceinline__ float dp_wave(const float* tile, int j32) {
  const float INF = __builtin_inff();
  float A = INF;
  for (int d = 0; d < 63; ++d) {
    float left = __shfl_up(A, 1, 32);
    if (j32 == 0) left = INF;
    int i = d - j32;
    int ii = i < 0 ? 0 : (i > 31 ? 31 : i);
    float dv = tile[(ii << 5) + j32];
    float up = (i == 0) ? (j32 == 0 ? 0.f : INF) : A;
    A = (i >= 0 && i < 32) ? (fminf(up, left) + dv) : INF;
  }
  return A;  // valid at j32 == 31
}

// K1: centers (mean over K), bf16 centers, bf16 feature copy, row norms. (R5-proven)
__global__ __launch_bounds__(256) void k_centers(const float* __restrict__ feat,
    unsigned short* __restrict__ cbf, unsigned short* __restrict__ fbf,
    float* __restrict__ cnorm, float* __restrict__ fnorm) {
  int row = blockIdx.x;            // p*32 + h
  int p = row >> 5, h = row & 31;
  int tid = threadIdx.x;
  int d0 = tid * 8;
  float c[8];
  float red[9];
  #pragma unroll
  for (int e = 0; e < 8; ++e) c[e] = 0.f;
  #pragma unroll
  for (int k = 0; k < KK; ++k) {
    size_t frow = (size_t)((p*KK + k)*HH + h);
    const float* src = feat + frow*DD + d0;
    float4v f0 = *(const float4v*)src;
    float4v f1 = *(const float4v*)(src + 4);
    float s = 0.f;
    #pragma unroll
    for (int e = 0; e < 4; ++e) {
      c[e]   += f0[e];
      c[4+e] += f1[e];
      s += f0[e]*f0[e] + f1[e]*f1[e];
    }
    red[k] = s;
    unsigned int fk[4];
    #pragma unroll
    for (int e = 0; e < 2; ++e) {
      fk[e]   = (unsigned int)f2bf(f0[2*e]) | ((unsigned int)f2bf(f0[2*e+1]) << 16);
      fk[2+e] = (unsigned int)f2bf(f1[2*e]) | ((unsigned int)f2bf(f1[2*e+1]) << 16);
    }
    *(uint4*)(fbf + frow*DD + d0) = make_uint4(fk[0], fk[1], fk[2], fk[3]);
  }
  float csq = 0.f;
  #pragma unroll
  for (int e = 0; e < 8; ++e) { c[e] *= 0.125f; csq += c[e]*c[e]; }
  unsigned int pk[4];
  #pragma unroll
  for (int e = 0; e < 4; ++e)
    pk[e] = (unsigned int)f2bf(c[2*e]) | ((unsigned int)f2bf(c[2*e+1]) << 16);
  *(uint4*)(cbf + (size_t)row*DD + d0) = make_uint4(pk[0], pk[1], pk[2], pk[3]);
  red[8] = csq;

  __shared__ float lred[4][9];
  int lane = tid & 63, wv = tid >> 6;
  #pragma unroll
  for (int r = 0; r < 9; ++r) {
    float v = red[r];
    #pragma unroll
    for (int off = 32; off > 0; off >>= 1) v += __shfl_down(v, off, 64);
    if (lane == 0) lred[wv][r] = v;
  }
  __syncthreads();
  if (tid < 9) {
    float s = lred[0][tid] + lred[1][tid] + lred[2][tid] + lred[3][tid];
    if (tid < 8) fnorm[((size_t)(p*KK + tid))*HH + h] = s;
    else         cnorm[row] = s;
  }
}

// K2: merged Gram + fused DP.
// Blocks 0..527  : inter (upper-tri 64x64 tiles; wave = pair; DP in epilogue -> inter_full).
// Blocks 528..1039: intra (class p, block jb; bf16 fbf source; DP in epilogue -> intra_pk).
__global__ __launch_bounds__(256) void k_gram(const unsigned short* __restrict__ cbf,
    const unsigned short* __restrict__ fbf, const float* __restrict__ cnorm,
    const float* __restrict__ fnorm, float* __restrict__ inter_full,
    float* __restrict__ intra_pk) {
  __shared__ char smem[32768];
  int tid = threadIdx.x, lane = tid & 63, w = tid >> 6;
  int ln = lane & 15, kq = lane >> 4;

  if (blockIdx.x < 528) {
    // ---------------- inter path ----------------
    unsigned short* Ab = (unsigned short*)smem;             // [2][4096]
    unsigned short* Bb = (unsigned short*)(smem + 16384);   // [2][4096]
    int bid = (blockIdx.x & 7)*66 + (blockIdx.x >> 3);      // 528 = 8*66, bijective
    int tI = 0, rem = bid;
    while (rem >= 32 - tI) { rem -= 32 - tI; ++tI; }
    int tJ = tI + rem;
    int wr = w >> 1, wc = w & 1;
    f32x4 acc[2][2];
    #pragma unroll
    for (int a = 0; a < 2; ++a)
      #pragma unroll
      for (int b = 0; b < 2; ++b)
        #pragma unroll
        for (int e = 0; e < 4; ++e) acc[a][b][e] = 0.f;

    int sr = lane >> 3, sc = lane & 7;
    int jch0 = sc ^ sr;
    const unsigned short* gA0 = cbf + (size_t)(tI*64 + w*16 + sr)*DD + jch0*8;
    const unsigned short* gB0 = cbf + (size_t)(tJ*64 + w*16 + sr)*DD + jch0*8;
    int lofs = w*1024 + lane*8;

    int aoff[2][2], boff[2][2];
    #pragma unroll
    for (int ks = 0; ks < 2; ++ks) {
      int phys = ((ks*4 + kq) ^ (ln & 7))*8;
      #pragma unroll
      for (int mt = 0; mt < 2; ++mt) {
        aoff[ks][mt] = (wr*32 + mt*16 + ln)*64 + phys;
        boff[ks][mt] = (wc*32 + mt*16 + ln)*64 + phys;
      }
    }

    gload_lds16(gA0,        Ab + lofs);
    gload_lds16(gA0 + 8*DD, Ab + lofs + 512);
    gload_lds16(gB0,        Bb + lofs);
    gload_lds16(gB0 + 8*DD, Bb + lofs + 512);
    asm volatile("s_waitcnt vmcnt(0)" ::: "memory");
    __builtin_amdgcn_s_barrier();

    int cur = 0;
    for (int t = 0; t < 32; ++t) {
      if (t < 31) {
        int k0 = (t + 1) * 64;
        gload_lds16(gA0 + k0,        Ab + (cur^1)*4096 + lofs);
        gload_lds16(gA0 + 8*DD + k0, Ab + (cur^1)*4096 + lofs + 512);
        gload_lds16(gB0 + k0,        Bb + (cur^1)*4096 + lofs);
        gload_lds16(gB0 + 8*DD + k0, Bb + (cur^1)*4096 + lofs + 512);
      }
      #pragma unroll
      for (int ks = 0; ks < 2; ++ks) {
        bf16x8 af[2], bfr[2];
        #pragma unroll
        for (int mt = 0; mt < 2; ++mt) {
          af[mt]  = *(const bf16x8*)(Ab + cur*4096 + aoff[ks][mt]);
          bfr[mt] = *(const bf16x8*)(Bb + cur*4096 + boff[ks][mt]);
        }
        #pragma unroll
        for (int mt = 0; mt < 2; ++mt)
          #pragma unroll
          for (int nt = 0; nt < 2; ++nt)
            acc[mt][nt] = __builtin_amdgcn_mfma_f32_16x16x32_bf16(af[mt], bfr[nt], acc[mt][nt], 0, 0, 0);
      }
      asm volatile("s_waitcnt vmcnt(0)" ::: "memory");
      __builtin_amdgcn_s_barrier();
      cur ^= 1;
    }

    // epilogue: tanh -> wave-private LDS tile -> in-wave DP -> inter_full (+mirror)
    int a = tI*2 + wr, b = tJ*2 + wc;
    bool own = (a < b);
    float* tile = (float*)(smem + w*4096);
    if (own) {
      #pragma unroll
      for (int mt = 0; mt < 2; ++mt) {
        #pragma unroll
        for (int nt = 0; nt < 2; ++nt) {
          int j  = nt*16 + ln;
          int cc = tJ*64 + wc*32 + j;
          float nc = cnorm[cc];
          #pragma unroll
          for (int v = 0; v < 4; ++v) {
            int i  = mt*16 + kq*4 + v;
            int rr = tI*64 + wr*32 + i;
            float d2 = cnorm[rr] + nc - 2.f*acc[mt][nt][v];
            tile[(i << 5) + j] = tanhf(0.5f*sqrtf(fmaxf(d2, 1e-12f)));
          }
        }
      }
    }
    __syncthreads();
    if (own) {
      float A = dp_wave(tile, lane & 31);
      if (lane == 31) {
        inter_full[a*64 + b] = A;
        inter_full[b*64 + a] = A;
      }
    }
  } else {
    // ---------------- intra path (R5-proven staging, bf16 fbf source) ----------------
    int bid = (int)blockIdx.x - 528;
    int p = bid >> 3, jb = bid & 7;
    int ks = w >> 1, nt = w & 1;
    unsigned short* A16 = (unsigned short*)smem;            // [2][2048] bf16
    unsigned short* B16 = (unsigned short*)(smem + 8192);   // [2][2048] bf16
    f32x4 acc[2];
    #pragma unroll
    for (int mi = 0; mi < 2; ++mi)
      #pragma unroll
      for (int e = 0; e < 4; ++e) acc[mi][e] = 0.f;

    int sr = lane >> 3, sc = lane & 7;
    int jch0 = sc ^ sr;
    int hw = w & 1;
    const unsigned short* g0 = (w < 2)
        ? cbf + (size_t)(p*32 + hw*16 + sr)*DD + jch0*8
        : fbf + (size_t)(p*256 + jb*32 + hw*16 + sr)*DD + jch0*8;
    int lofs = hw*1024 + lane*8;
    unsigned short* sbase = (w < 2) ? A16 : B16;

    int phys = ((ks*4 + kq) ^ (ln & 7))*8;
    int aofs[2];
    #pragma unroll
    for (int mi = 0; mi < 2; ++mi) aofs[mi] = (mi*16 + ln)*64 + phys;
    int bofs = (nt*16 + ln)*64 + phys;

    gload_lds16(g0,        sbase + lofs);
    gload_lds16(g0 + 8*DD, sbase + lofs + 512);
    asm volatile("s_waitcnt vmcnt(0)" ::: "memory");
    __builtin_amdgcn_s_barrier();

    int cur = 0;
    for (int t = 0; t < 32; ++t) {
      if (t < 31) {
        int k0 = (t + 1) * 64;
        gload_lds16(g0 + k0,        sbase + (cur^1)*2048 + lofs);
        gload_lds16(g0 + 8*DD + k0, sbase + (cur^1)*2048 + lofs + 512);
      }
      bf16x8 bfr = *(const bf16x8*)(B16 + cur*2048 + bofs);
      #pragma unroll
      for (int mi = 0; mi < 2; ++mi) {
        bf16x8 af = *(const bf16x8*)(A16 + cur*2048 + aofs[mi]);
        acc[mi] = __builtin_amdgcn_mfma_f32_16x16x32_bf16(af, bfr, acc[mi], 0, 0, 0);
      }
      asm volatile("s_waitcnt vmcnt(0)" ::: "memory");
      __builtin_amdgcn_s_barrier();
      cur ^= 1;
    }

    // K-split reduce: waves 2,3 (ks=1) -> waves 0,1 (ks=0), matched nt
    float* fb = (float*)smem;
    float* tile = (float*)(smem + 16384);   // 32x32 pair tile
    __syncthreads();
    if (w >= 2) {
      #pragma unroll
      for (int mi = 0; mi < 2; ++mi)
        *(f32x4*)(fb + ((w - 2)*2 + mi)*256 + lane*4) = acc[mi];
    }
    __syncthreads();
    if (w < 2) {
      #pragma unroll
      for (int mi = 0; mi < 2; ++mi)
        acc[mi] += *(const f32x4*)(fb + (w*2 + mi)*256 + lane*4);
      int cl = jb*32 + nt*16 + ln;
      float nf = fnorm[(size_t)p*256 + cl];
      #pragma unroll
      for (int mi = 0; mi < 2; ++mi) {
        #pragma unroll
        for (int v = 0; v < 4; ++v) {
          int i = mi*16 + kq*4 + v;
          float d2 = cnorm[p*32 + i] + nf - 2.f*acc[mi][v];
          tile[(i << 5) + (nt*16 + ln)] = tanhf(0.5f*sqrtf(fmaxf(d2, 1e-12f)));
        }
      }
    }
    __syncthreads();
    if (w == 0) {
      float A = dp_wave(tile, lane & 31);
      if (lane == 31) intra_pk[p*8 + jb] = A;
    }
  }
}

// K3: reductions + loss. out = [loss, intra_max[64], inter_min[64]]
__global__ __launch_bounds__(64) void k_final(const float* __restrict__ inter_full,
    const float* __restrict__ intra_pk, float* __restrict__ out) {
  int p = threadIdx.x;
  const float INF = __builtin_inff();
  float mn = INF;
  #pragma unroll 8
  for (int b = 0; b < 64; ++b)
    if (b != p) mn = fminf(mn, inter_full[p*64 + b]);
  float mx = -INF;
  #pragma unroll
  for (int k = 0; k < 8; ++k) mx = fmaxf(mx, intra_pk[p*8 + k]);
  out[1 + p]  = mx;
  out[65 + p] = mn;
  float v = fmaxf(mx - mn + 10.0f, 0.0f);
  #pragma unroll
  for (int off = 32; off > 0; off >>= 1) v += __shfl_down(v, off, 64);
  if (p == 0) out[0] = v * (1.0f/64.0f);
}

extern "C" void kernel_launch(void* const* d_in, const int* in_sizes, int n_in,
                              void* d_out, int out_size, void* d_ws, size_t ws_size,
                              hipStream_t stream) {
  const float* feat = (const float*)d_in[0];
  float* out = (float*)d_out;
  char* w = (char*)d_ws;
  // workspace layout (bytes)
  unsigned short* cbf = (unsigned short*)w;                 // 8,388,608
  unsigned short* fbf = (unsigned short*)(w + 8388608);     // 67,108,864
  float* cnorm        = (float*)(w + 75497472);             // 8,192
  float* fnorm        = (float*)(w + 75505664);             // 65,536
  float* inter_full   = (float*)(w + 75571200);             // 16,384
  float* intra_pk     = (float*)(w + 75587584);             // 2,048
  // total ~75.6 MB

  k_centers<<<RR, 256, 0, stream>>>(feat, cbf, fbf, cnorm, fnorm);
  k_gram<<<1040, 256, 0, stream>>>(cbf, fbf, cnorm, fnorm, inter_full, intra_pk);
  k_final<<<1, 64, 0, stream>>>(inter_full, intra_pk, out);
}

// Round 8
// 85.177 us; speedup vs baseline: 1.2362x; 1.0322x over previous
//
#include <hip/hip_runtime.h>
#include <cstdint>
#include <cstddef>

#define PP 64
#define KK 8
#define HH 32
#define DD 2048
#define RR (PP*HH)        // 2048 center rows

typedef __attribute__((ext_vector_type(4))) float  f32x4;
typedef __attribute__((ext_vector_type(4))) float  float4v;
typedef __attribute__((ext_vector_type(8))) __bf16 bf16x8;

__device__ __forceinline__ unsigned short f2bf(float f) {
  unsigned int u = __builtin_bit_cast(unsigned int, f);
  u += 0x7fffu + ((u >> 16) & 1u);
  return (unsigned short)(u >> 16);
}

__device__ __forceinline__ void gload_lds16(const void* g, void* l) {
  __builtin_amdgcn_global_load_lds(
      (const __attribute__((address_space(1))) void*)g,
      (__attribute__((address_space(3))) void*)l, 16, 0, 0);
}

// Proven 63-step anti-diagonal wavefront DP over a 32x32 tile (lanes 0..31 active).
__device__ __forceinline__ float dp_wave(const float* tile, int j32) {
  const float INF = __builtin_inff();
  float A = INF;
  for (int d = 0; d < 63; ++d) {
    float left = __shfl_up(A, 1, 32);
    if (j32 == 0) left = INF;
    int i = d - j32;
    int ii = i < 0 ? 0 : (i > 31 ? 31 : i);
    float dv = tile[(ii << 5) + j32];
    float up = (i == 0) ? (j32 == 0 ? 0.f : INF) : A;
    A = (i >= 0 && i < 32) ? (fminf(up, left) + dv) : INF;
  }
  return A;  // valid at j32 == 31
}

// K1: centers (mean over K), bf16 centers, bf16 feature copy, row norms. (R5/R7-proven)
__global__ __launch_bounds__(256) void k_centers(const float* __restrict__ feat,
    unsigned short* __restrict__ cbf, unsigned short* __restrict__ fbf,
    float* __restrict__ cnorm, float* __restrict__ fnorm) {
  int row = blockIdx.x;            // p*32 + h
  int p = row >> 5, h = row & 31;
  int tid = threadIdx.x;
  int d0 = tid * 8;
  float c[8];
  float red[9];
  #pragma unroll
  for (int e = 0; e < 8; ++e) c[e] = 0.f;
  #pragma unroll
  for (int k = 0; k < KK; ++k) {
    size_t frow = (size_t)((p*KK + k)*HH + h);
    const float* src = feat + frow*DD + d0;
    float4v f0 = *(const float4v*)src;
    float4v f1 = *(const float4v*)(src + 4);
    float s = 0.f;
    #pragma unroll
    for (int e = 0; e < 4; ++e) {
      c[e]   += f0[e];
      c[4+e] += f1[e];
      s += f0[e]*f0[e] + f1[e]*f1[e];
    }
    red[k] = s;
    unsigned int fk[4];
    #pragma unroll
    for (int e = 0; e < 2; ++e) {
      fk[e]   = (unsigned int)f2bf(f0[2*e]) | ((unsigned int)f2bf(f0[2*e+1]) << 16);
      fk[2+e] = (unsigned int)f2bf(f1[2*e]) | ((unsigned int)f2bf(f1[2*e+1]) << 16);
    }
    *(uint4*)(fbf + frow*DD + d0) = make_uint4(fk[0], fk[1], fk[2], fk[3]);
  }
  float csq = 0.f;
  #pragma unroll
  for (int e = 0; e < 8; ++e) { c[e] *= 0.125f; csq += c[e]*c[e]; }
  unsigned int pk[4];
  #pragma unroll
  for (int e = 0; e < 4; ++e)
    pk[e] = (unsigned int)f2bf(c[2*e]) | ((unsigned int)f2bf(c[2*e+1]) << 16);
  *(uint4*)(cbf + (size_t)row*DD + d0) = make_uint4(pk[0], pk[1], pk[2], pk[3]);
  red[8] = csq;

  __shared__ float lred[4][9];
  int lane = tid & 63, wv = tid >> 6;
  #pragma unroll
  for (int r = 0; r < 9; ++r) {
    float v = red[r];
    #pragma unroll
    for (int off = 32; off > 0; off >>= 1) v += __shfl_down(v, off, 64);
    if (lane == 0) lred[wv][r] = v;
  }
  __syncthreads();
  if (tid < 9) {
    float s = lred[0][tid] + lred[1][tid] + lred[2][tid] + lred[3][tid];
    if (tid < 8) fnorm[((size_t)(p*KK + tid))*HH + h] = s;
    else         cnorm[row] = s;
  }
}

// K2: merged Gram + fused DP, 3-buffer depth-2 counted-vmcnt pipeline.
// Blocks 0..527  : inter (upper-tri 64x64 tiles; wave = pair; DP epilogue -> inter_full).
// Blocks 528..1039: intra (class p, block jb; bf16 fbf source; DP epilogue -> intra_pk).
__global__ __launch_bounds__(256) void k_gram(const unsigned short* __restrict__ cbf,
    const unsigned short* __restrict__ fbf, const float* __restrict__ cnorm,
    const float* __restrict__ fnorm, float* __restrict__ inter_full,
    float* __restrict__ intra_pk) {
  __shared__ char smem[49152];   // 3 x 16 KB (inter) / 3 x 8 KB + spare (intra)
  int tid = threadIdx.x, lane = tid & 63, w = tid >> 6;
  int ln = lane & 15, kq = lane >> 4;

  if (blockIdx.x < 528) {
    // ---------------- inter path ----------------
    int bid = (blockIdx.x & 7)*66 + (blockIdx.x >> 3);      // 528 = 8*66, bijective
    int tI = 0, rem = bid;
    while (rem >= 32 - tI) { rem -= 32 - tI; ++tI; }
    int tJ = tI + rem;
    int wr = w >> 1, wc = w & 1;
    f32x4 acc[2][2];
    #pragma unroll
    for (int a = 0; a < 2; ++a)
      #pragma unroll
      for (int b = 0; b < 2; ++b)
        #pragma unroll
        for (int e = 0; e < 4; ++e) acc[a][b][e] = 0.f;

    int sr = lane >> 3, sc = lane & 7;
    int jch0 = sc ^ sr;
    const unsigned short* gA0 = cbf + (size_t)(tI*64 + w*16 + sr)*DD + jch0*8;
    const unsigned short* gB0 = cbf + (size_t)(tJ*64 + w*16 + sr)*DD + jch0*8;
    int lofs = w*1024 + lane*8;

    int aoff[2][2], boff[2][2];
    #pragma unroll
    for (int ks = 0; ks < 2; ++ks) {
      int phys = ((ks*4 + kq) ^ (ln & 7))*8;
      #pragma unroll
      for (int mt = 0; mt < 2; ++mt) {
        aoff[ks][mt] = (wr*32 + mt*16 + ln)*64 + phys;
        boff[ks][mt] = (wc*32 + mt*16 + ln)*64 + phys;
      }
    }

    auto stage = [&](int tt, int bi) {
      int k0 = tt * 64;
      unsigned short* A = (unsigned short*)(smem + bi*16384);
      unsigned short* B = A + 4096;
      gload_lds16(gA0 + k0,        A + lofs);
      gload_lds16(gA0 + 8*DD + k0, A + lofs + 512);
      gload_lds16(gB0 + k0,        B + lofs);
      gload_lds16(gB0 + 8*DD + k0, B + lofs + 512);
    };
    auto do_step = [&](int bi) {
      const unsigned short* A = (const unsigned short*)(smem + bi*16384);
      const unsigned short* B = A + 4096;
      #pragma unroll
      for (int ks = 0; ks < 2; ++ks) {
        bf16x8 af[2], bfr[2];
        #pragma unroll
        for (int mt = 0; mt < 2; ++mt) {
          af[mt]  = *(const bf16x8*)(A + aoff[ks][mt]);
          bfr[mt] = *(const bf16x8*)(B + boff[ks][mt]);
        }
        #pragma unroll
        for (int mt = 0; mt < 2; ++mt)
          #pragma unroll
          for (int nt = 0; nt < 2; ++nt)
            acc[mt][nt] = __builtin_amdgcn_mfma_f32_16x16x32_bf16(af[mt], bfr[nt], acc[mt][nt], 0, 0, 0);
      }
    };

    // prologue: tiles 0,1 in flight (8 loads/wave); wait tile0 (4 newest outstanding ok)
    stage(0, 0);
    stage(1, 1);
    asm volatile("s_waitcnt vmcnt(4)" ::: "memory");
    __builtin_amdgcn_s_barrier();
    // steady state: compute t while t+1 ready and t+2 in flight
    for (int t = 0; t < 30; ++t) {
      stage(t + 2, (t + 2) % 3);
      do_step(t % 3);
      asm volatile("s_waitcnt vmcnt(4)" ::: "memory");   // t+1's loads complete
      __builtin_amdgcn_s_barrier();
    }
    do_step(0);                                           // t=30 (30%3==0)
    asm volatile("s_waitcnt vmcnt(0)" ::: "memory");      // t=31's loads complete
    __builtin_amdgcn_s_barrier();
    do_step(1);                                           // t=31 (31%3==1)
    __syncthreads();

    // epilogue: tanh -> wave-private LDS tile -> in-wave DP -> inter_full (+mirror)
    int a = tI*2 + wr, b = tJ*2 + wc;
    bool own = (a < b);
    float* tile = (float*)(smem + w*4096);
    if (own) {
      #pragma unroll
      for (int mt = 0; mt < 2; ++mt) {
        #pragma unroll
        for (int nt = 0; nt < 2; ++nt) {
          int j  = nt*16 + ln;
          int cc = tJ*64 + wc*32 + j;
          float nc = cnorm[cc];
          #pragma unroll
          for (int v = 0; v < 4; ++v) {
            int i  = mt*16 + kq*4 + v;
            int rr = tI*64 + wr*32 + i;
            float d2 = cnorm[rr] + nc - 2.f*acc[mt][nt][v];
            tile[(i << 5) + j] = tanhf(0.5f*sqrtf(fmaxf(d2, 1e-12f)));
          }
        }
      }
    }
    __syncthreads();
    if (own) {
      float A = dp_wave(tile, lane & 31);
      if (lane == 31) {
        inter_full[a*64 + b] = A;
        inter_full[b*64 + a] = A;
      }
    }
  } else {
    // ---------------- intra path ----------------
    int bid = (int)blockIdx.x - 528;
    int p = bid >> 3, jb = bid & 7;
    int ks = w >> 1, nt = w & 1;
    f32x4 acc[2];
    #pragma unroll
    for (int mi = 0; mi < 2; ++mi)
      #pragma unroll
      for (int e = 0; e < 4; ++e) acc[mi][e] = 0.f;

    int sr = lane >> 3, sc = lane & 7;
    int jch0 = sc ^ sr;
    int hw = w & 1;
    const unsigned short* g0 = (w < 2)
        ? cbf + (size_t)(p*32 + hw*16 + sr)*DD + jch0*8
        : fbf + (size_t)(p*256 + jb*32 + hw*16 + sr)*DD + jch0*8;
    int lofs = hw*1024 + lane*8;
    int isB = (w >= 2);

    int phys = ((ks*4 + kq) ^ (ln & 7))*8;
    int aofs[2];
    #pragma unroll
    for (int mi = 0; mi < 2; ++mi) aofs[mi] = (mi*16 + ln)*64 + phys;
    int bofs = (nt*16 + ln)*64 + phys;

    auto stage = [&](int tt, int bi) {
      int k0 = tt * 64;
      unsigned short* S = (unsigned short*)(smem + bi*8192) + isB*2048;
      gload_lds16(g0 + k0,        S + lofs);
      gload_lds16(g0 + 8*DD + k0, S + lofs + 512);
    };
    auto do_step = [&](int bi) {
      const unsigned short* A16 = (const unsigned short*)(smem + bi*8192);
      const unsigned short* B16 = A16 + 2048;
      bf16x8 bfr = *(const bf16x8*)(B16 + bofs);
      #pragma unroll
      for (int mi = 0; mi < 2; ++mi) {
        bf16x8 af = *(const bf16x8*)(A16 + aofs[mi]);
        acc[mi] = __builtin_amdgcn_mfma_f32_16x16x32_bf16(af, bfr, acc[mi], 0, 0, 0);
      }
    };

    stage(0, 0);
    stage(1, 1);
    asm volatile("s_waitcnt vmcnt(2)" ::: "memory");
    __builtin_amdgcn_s_barrier();
    for (int t = 0; t < 30; ++t) {
      stage(t + 2, (t + 2) % 3);
      do_step(t % 3);
      asm volatile("s_waitcnt vmcnt(2)" ::: "memory");
      __builtin_amdgcn_s_barrier();
    }
    do_step(0);
    asm volatile("s_waitcnt vmcnt(0)" ::: "memory");
    __builtin_amdgcn_s_barrier();
    do_step(1);

    // K-split reduce: waves 2,3 (ks=1) -> waves 0,1 (ks=0), matched nt
    float* fb = (float*)smem;
    float* tile = (float*)(smem + 16384);   // 32x32 pair tile
    __syncthreads();
    if (w >= 2) {
      #pragma unroll
      for (int mi = 0; mi < 2; ++mi)
        *(f32x4*)(fb + ((w - 2)*2 + mi)*256 + lane*4) = acc[mi];
    }
    __syncthreads();
    if (w < 2) {
      #pragma unroll
      for (int mi = 0; mi < 2; ++mi)
        acc[mi] += *(const f32x4*)(fb + (w*2 + mi)*256 + lane*4);
      int cl = jb*32 + nt*16 + ln;
      float nf = fnorm[(size_t)p*256 + cl];
      #pragma unroll
      for (int mi = 0; mi < 2; ++mi) {
        #pragma unroll
        for (int v = 0; v < 4; ++v) {
          int i = mi*16 + kq*4 + v;
          float d2 = cnorm[p*32 + i] + nf - 2.f*acc[mi][v];
          tile[(i << 5) + (nt*16 + ln)] = tanhf(0.5f*sqrtf(fmaxf(d2, 1e-12f)));
        }
      }
    }
    __syncthreads();
    if (w == 0) {
      float A = dp_wave(tile, lane & 31);
      if (lane == 31) intra_pk[p*8 + jb] = A;
    }
  }
}

// K3: reductions + loss. out = [loss, intra_max[64], inter_min[64]]
__global__ __launch_bounds__(64) void k_final(const float* __restrict__ inter_full,
    const float* __restrict__ intra_pk, float* __restrict__ out) {
  int p = threadIdx.x;
  const float INF = __builtin_inff();
  float mn = INF;
  #pragma unroll 8
  for (int b = 0; b < 64; ++b)
    if (b != p) mn = fminf(mn, inter_full[p*64 + b]);
  float mx = -INF;
  #pragma unroll
  for (int k = 0; k < 8; ++k) mx = fmaxf(mx, intra_pk[p*8 + k]);
  out[1 + p]  = mx;
  out[65 + p] = mn;
  float v = fmaxf(mx - mn + 10.0f, 0.0f);
  #pragma unroll
  for (int off = 32; off > 0; off >>= 1) v += __shfl_down(v, off, 64);
  if (p == 0) out[0] = v * (1.0f/64.0f);
}

extern "C" void kernel_launch(void* const* d_in, const int* in_sizes, int n_in,
                              void* d_out, int out_size, void* d_ws, size_t ws_size,
                              hipStream_t stream) {
  const float* feat = (const float*)d_in[0];
  float* out = (float*)d_out;
  char* w = (char*)d_ws;
  // workspace layout (bytes)
  unsigned short* cbf = (unsigned short*)w;                 // 8,388,608
  unsigned short* fbf = (unsigned short*)(w + 8388608);     // 67,108,864
  float* cnorm        = (float*)(w + 75497472);             // 8,192
  float* fnorm        = (float*)(w + 75505664);             // 65,536
  float* inter_full   = (float*)(w + 75571200);             // 16,384
  float* intra_pk     = (float*)(w + 75587584);             // 2,048
  // total ~75.6 MB

  k_centers<<<RR, 256, 0, stream>>>(feat, cbf, fbf, cnorm, fnorm);
  k_gram<<<1040, 256, 0, stream>>>(cbf, fbf, cnorm, fnorm, inter_full, intra_pk);
  k_final<<<1, 64, 0, stream>>>(inter_full, intra_pk, out);
}